// Round 12
// baseline (2993.630 us; speedup 1.0000x reference)
//
#include <hip/hip_runtime.h>
#include <stdint.h>

#define B_SZ  8192
#define S_DIM 512
#define H_DIM 2048
#define KIN   576
#define OUT_MS 4194304  // B*S

typedef unsigned short u16;
typedef u16   u16x8 __attribute__((ext_vector_type(8)));
typedef u16   u16x4 __attribute__((ext_vector_type(4)));
typedef short s16x8 __attribute__((ext_vector_type(8)));
typedef float f32x4 __attribute__((ext_vector_type(4)));

__device__ __forceinline__ float b2f(u16 u) {
    union { unsigned int i; float f; } v; v.i = ((unsigned int)u) << 16; return v.f;
}
__device__ __forceinline__ u16 f2b(float f) {
    union { float f; unsigned int i; } v; v.f = f;
    unsigned int u = v.i;
    return (u16)((u + 0x7FFFu + ((u >> 16) & 1u)) >> 16);  // RNE
}
// tanh-form GELU via sigmoid: y*sigma(1.59577*y*(1+0.044715*y^2)); |err|<=~1e-3
__device__ __forceinline__ float gelu_f(float y) {
    const float t = __expf(-1.5957691216f * y * (1.0f + 0.044715f * y * y));
    return y / (1.0f + t);
}

__device__ __forceinline__ void gload_lds16(const void* gp, void* lp) {
    __builtin_amdgcn_global_load_lds(
        (const __attribute__((address_space(1))) unsigned int*)gp,
        (__attribute__((address_space(3))) unsigned int*)(unsigned int)(uintptr_t)lp,
        16, 0, 0);
}

#define MFMA __builtin_amdgcn_mfma_f32_16x16x32_bf16

// ---------------- concat + cast to bf16 ------------------------------------
__global__ __launch_bounds__(256) void k_concat(
    const float* __restrict__ state, const float* __restrict__ action,
    u16* __restrict__ xb)
{
    int idx = blockIdx.x * 256 + threadIdx.x;
    int b = idx / KIN, c = idx - b * KIN;
    float v = (c < S_DIM) ? state[(size_t)b * S_DIM + c]
                          : action[(size_t)b * 64 + (c - S_DIM)];
    xb[idx] = f2b(v);
}

// ---------------- f32 -> bf16 cast of 6 param arrays into one ws buffer -----
__global__ __launch_bounds__(256) void k_cast(
    const float* __restrict__ p0, const float* __restrict__ p1,
    const float* __restrict__ p2, const float* __restrict__ p3,
    const float* __restrict__ p4, const float* __restrict__ p5,
    u16* __restrict__ dst)
{
    int i = blockIdx.x * 256 + threadIdx.x;   // grid covers 163840
    float v;
    if      (i < 16384)  v = p0[i];
    else if (i < 32768)  v = p1[i - 16384];
    else if (i < 81920)  v = p2[i - 32768];
    else if (i < 131072) v = p3[i - 81920];
    else if (i < 147456) v = p4[i - 131072];
    else                 v = p5[i - 147456];
    dst[i] = f2b(v);
}

// ---------------- weights f32 [K][N] -> bf16 fragment-major (16x16x32) -------
// Line id = (fnb*NKT + kt)*2 + h, one 1KB line per (16-col block, K-tile, half):
//   Wf[lid*512 + lane*8 + j] = W[kt*64 + h*32 + (lane>>4)*8 + j][fnb*16 + (lane&15)]
// Reading 16B at lane*16 gives exactly the MFMA "A-operand" fragment for the
// swapped-operand call (n = lane&15, k = (lane>>4)*8+j), matching R5's verified
// LDS boff mapping with the swizzle removed.
__global__ __launch_bounds__(256) void k_wfrag16(
    const float* __restrict__ W, u16* __restrict__ Wf, int Kd, int Nd)
{
    const int NKT = Kd >> 6;
    const int gid = blockIdx.x * 256 + threadIdx.x;
    const int lane = gid & 63, lid = gid >> 6;
    const int h = lid & 1, rest = lid >> 1;
    const int kt = rest % NKT, fnb = rest / NKT;
    const int n = fnb * 16 + (lane & 15);
    const int k0 = kt * 64 + h * 32 + (lane >> 4) * 8;
    const size_t mo = (size_t)blockIdx.z * Kd * Nd;
    const float* src = W + mo + (size_t)k0 * Nd + n;
    u16x8 o;
#pragma unroll
    for (int j = 0; j < 8; ++j) o[j] = f2b(src[(size_t)j * Nd]);
    *(u16x8*)&Wf[mo + (size_t)lid * 512 + lane * 8] = o;
}

// ---------------- 256x256 GEMM: A via LDS dbuf, B direct global->regs --------
// 512 thr = 8 waves (2M x 4N), wave tile 128x64. A-path byte-identical to the
// verified R5 kernel (swizzled staging + LDS fragment reads, conflicts=0).
// B fragments live in registers, loaded per-wave from fragment-major Wf
// (8 x 1KB coalesced loads per K-tile, L2/L3-hot weights) -> LDS traffic
// drops 256->160KB per K-tile and barriers drop 8->1 per K-tile (64 MFMA
// per barrier). Waits: manual vmcnt(8) covers A(t+1) (A issued before B);
// compiler auto-inserts vmcnt for B register uses.
// MODE 0: Z(u16)=bf16(acc+bias); MODE 1: P(f32)=state+acc+bias;
// MODE 2: c=state+acc+bias; sum_o+=c; sq_o+=c*c (non-atomic, seq e)
template<int MODE>
__global__ __launch_bounds__(512, 2) void k_gemm256(
    const u16* __restrict__ A, size_t sAe,
    const u16* __restrict__ Wf, size_t sBe,
    const float* __restrict__ bias, int sbE,
    void* __restrict__ Zv, size_t sZe,
    const float* __restrict__ st, float* __restrict__ sum_o, float* __restrict__ sq_o,
    int N, int K)
{
    __shared__ __align__(16) u16 lds[2][16384];   // A double-buffer, 32KB each
    const int t = threadIdx.x;
    const int lane = t & 63;
    const int wid = t >> 6;
    const int wm = wid >> 2, wn = wid & 3;

    // locality swizzle: e-major, per-XCD contiguous bx, by fastest (gx % 8 == 0)
    const int gx = gridDim.x, gy = gridDim.y;
    const int linb = blockIdx.x + gx * (blockIdx.y + gy * blockIdx.z);
    const int x  = linb & 7;
    const int s  = linb >> 3;
    const int m_ = (gx * gy) >> 3;
    const int bz = s / m_;
    const int r_ = s - bz * m_;
    const int p_ = r_ / gy;
    const int by = r_ - p_ * gy;
    const int bx = x * (gx >> 3) + p_;
    const int m0 = bx * 256, n0 = by * 256;

    const u16* Ab = A + (size_t)bz * sAe + (size_t)m0 * K;
    // A staging (R5-verified): one STG round = 64 rows x 64 cols, pre-swizzled src
    const int srow = t >> 3;
    const int scol = (((t & 7) ^ (srow & 7)) * 8);
    const int ldst = srow * 64 + (t & 7) * 8;
    const int NT = K >> 6;
    const u16* gA = Ab + (size_t)srow * K + scol;
    auto STGA = [&](int kt, u16* slab) {
#pragma unroll
        for (int r = 0; r < 4; ++r)
            gload_lds16(gA + (size_t)(r * 64) * K + kt * 64, slab + r * 4096 + ldst);
    };

    // B fragment base (fragment-major): fnb = n0/16 + wn*4 + nj
    const int NKT = NT;
    const u16* wq = Wf + (size_t)bz * sBe
                  + (size_t)((n0 >> 4) + wn * 4) * NKT * 1024 + (size_t)lane * 8;

    // A fragment LDS byte offsets (R5-verified swizzled reads)
    const int fr = lane & 15, hi = lane >> 4;
    const int cswz = (fr & 7) << 4;
    const int ac0 = (hi * 16) ^ cswz;
    const int ac1 = (64 + hi * 16) ^ cswz;
    const int ar0 = (wm * 128 + fr) * 128;
    const int ar1 = (wm * 128 + 16 + fr) * 128;

    f32x4 acc[8][4];
#pragma unroll
    for (int i = 0; i < 8; ++i)
#pragma unroll
        for (int j = 0; j < 4; ++j) acc[i][j] = (f32x4){0.f, 0.f, 0.f, 0.f};

    s16x8 bf0[4][2], bf1[4][2];
    s16x8 af[4];
    u16* slab0 = &lds[0][0];
    u16* slab1 = &lds[1][0];

#define LOADBG(BF, KT)                                                    \
    _Pragma("unroll") for (int nj = 0; nj < 4; ++nj) {                    \
        const u16* p_ = wq + ((size_t)nj * NKT + (KT)) * 1024;            \
        BF[nj][0] = *(const s16x8*)(p_);                                  \
        BF[nj][1] = *(const s16x8*)(p_ + 512);                            \
    }
#define LOADA(PA, Q)                                                      \
    af[0] = *(const s16x8*)((const char*)(PA) + (Q) * 4096 + ar0 + ac0);  \
    af[1] = *(const s16x8*)((const char*)(PA) + (Q) * 4096 + ar0 + ac1);  \
    af[2] = *(const s16x8*)((const char*)(PA) + (Q) * 4096 + ar1 + ac0);  \
    af[3] = *(const s16x8*)((const char*)(PA) + (Q) * 4096 + ar1 + ac1);
#define QMFMA(Q, BFC)                                                     \
    __builtin_amdgcn_s_setprio(1);                                        \
    _Pragma("unroll") for (int nj = 0; nj < 4; ++nj) {                    \
        acc[2*(Q)][nj]   = MFMA(BFC[nj][0], af[0], acc[2*(Q)][nj], 0, 0, 0);   \
        acc[2*(Q)][nj]   = MFMA(BFC[nj][1], af[1], acc[2*(Q)][nj], 0, 0, 0);   \
        acc[2*(Q)+1][nj] = MFMA(BFC[nj][0], af[2], acc[2*(Q)+1][nj], 0, 0, 0); \
        acc[2*(Q)+1][nj] = MFMA(BFC[nj][1], af[3], acc[2*(Q)+1][nj], 0, 0, 0); \
    }                                                                     \
    __builtin_amdgcn_s_setprio(0);
// One K-tile: issue A(t+1) staging + B(t+1) reg loads first (latency overlaps
// the MFMA body), then 4 quarters of {4 ds_read + 16 MFMA}, then a single
// vmcnt(8) [A(t+1) landed, B(t+1)x8 still in flight] + one barrier.
#define TILE(KT, BFC, BFN, LAc, LAn) {                                    \
    const bool h1_ = (KT) + 1 < NT;                                       \
    if (h1_) { STGA((KT) + 1, LAn); LOADBG(BFN, (KT) + 1) }               \
    LOADA(LAc, 0) QMFMA(0, BFC)                                           \
    LOADA(LAc, 1) QMFMA(1, BFC)                                           \
    LOADA(LAc, 2) QMFMA(2, BFC)                                           \
    LOADA(LAc, 3) QMFMA(3, BFC)                                           \
    if (h1_) { asm volatile("s_waitcnt vmcnt(8)" ::: "memory"); }         \
    else     { asm volatile("s_waitcnt vmcnt(0)" ::: "memory"); }         \
    __builtin_amdgcn_sched_barrier(0);                                    \
    __builtin_amdgcn_s_barrier(); }

    // prologue: A(0)->slab0 (4 loads), B(0)->regs (8 loads); wait A(0) only
    STGA(0, slab0);
    LOADBG(bf0, 0)
    asm volatile("s_waitcnt vmcnt(8)" ::: "memory");
    __builtin_amdgcn_sched_barrier(0);
    __builtin_amdgcn_s_barrier();

    int kt = 0;
    for (; kt + 1 < NT; kt += 2) {
        TILE(kt, bf0, bf1, slab0, slab1)
        TILE(kt + 1, bf1, bf0, slab1, slab0)
    }
    if (kt < NT) { TILE(kt, bf0, bf1, slab0, slab1) }
#undef LOADBG
#undef LOADA
#undef QMFMA
#undef TILE

    // epilogue (R5-verified swapped layout): M = m0+wm*128+mi*16+fr ;
    // N = n0+wn*64+nj*16+hi*4+r
    const float* biasp = bias + (size_t)bz * sbE;
    f32x4 bias4[4];
#pragma unroll
    for (int nj = 0; nj < 4; ++nj)
        bias4[nj] = *(const f32x4*)&biasp[n0 + wn * 64 + nj * 16 + hi * 4];
#pragma unroll
    for (int mi = 0; mi < 8; ++mi) {
        const int row = m0 + wm * 128 + mi * 16 + fr;
#pragma unroll
        for (int nj = 0; nj < 4; ++nj) {
            const int cb = n0 + wn * 64 + nj * 16 + hi * 4;
            const size_t idx = (size_t)row * N + cb;
            if (MODE == 0) {
                u16x4 o;
#pragma unroll
                for (int r = 0; r < 4; ++r) o[r] = f2b(acc[mi][nj][r] + bias4[nj][r]);
                *(u16x4*)&((u16*)Zv)[(size_t)bz * sZe + idx] = o;
            } else if (MODE == 1) {
                const f32x4 sv = *(const f32x4*)&st[idx];
                f32x4 c;
#pragma unroll
                for (int r = 0; r < 4; ++r) c[r] = sv[r] + acc[mi][nj][r] + bias4[nj][r];
                *(f32x4*)&((float*)Zv)[(size_t)bz * sZe + idx] = c;
            } else {
                const f32x4 sv = *(const f32x4*)&st[idx];
                f32x4 s1 = *(const f32x4*)&sum_o[idx];
                f32x4 s2 = *(const f32x4*)&sq_o[idx];
#pragma unroll
                for (int r = 0; r < 4; ++r) {
                    const float c = sv[r] + acc[mi][nj][r] + bias4[nj][r];
                    s1[r] += c; s2[r] += c * c;
                }
                *(f32x4*)&sum_o[idx] = s1;
                *(f32x4*)&sq_o[idx] = s2;
            }
        }
    }
}

// ---------------- LayerNorm + GELU (+residual, +fused heads), 2 rows/wave ----
template<int RES, int FIN>
__global__ __launch_bounds__(256) void k_ln(
    const u16* __restrict__ z, u16* __restrict__ h,
    const u16* __restrict__ g, const u16* __restrict__ be, int egb,
    const u16* __restrict__ wr, const u16* __restrict__ wd,
    const float* __restrict__ br, const float* __restrict__ bd,
    float* __restrict__ sum_rew, float* __restrict__ sum_done)
{
    const int lane = threadIdx.x & 63;
    const int w = threadIdx.x >> 6;
    const int e = blockIdx.z;
    const int row0 = blockIdx.x * 8 + w * 2;
    const size_t base0 = ((size_t)e * B_SZ + row0) * H_DIM;
    const u16* gp = g + (size_t)e * egb;
    const u16* bp = be + (size_t)e * egb;

    u16x8 zv[2][4], gv[4], bv[4], hv[2][4];
#pragma unroll
    for (int j = 0; j < 4; ++j) {
        const int c = j * 512 + lane * 8;
        zv[0][j] = *(const u16x8*)&z[base0 + c];
        zv[1][j] = *(const u16x8*)&z[base0 + H_DIM + c];
        gv[j] = *(const u16x8*)&gp[c];
        bv[j] = *(const u16x8*)&bp[c];
        if (RES) {
            hv[0][j] = *(const u16x8*)&h[base0 + c];
            hv[1][j] = *(const u16x8*)&h[base0 + H_DIM + c];
        }
    }
    float s0 = 0.f, q0 = 0.f, s1 = 0.f, q1 = 0.f;
#pragma unroll
    for (int j = 0; j < 4; ++j)
#pragma unroll
        for (int k = 0; k < 8; ++k) {
            const float f0 = b2f(zv[0][j][k]); s0 += f0; q0 += f0 * f0;
            const float f1 = b2f(zv[1][j][k]); s1 += f1; q1 += f1 * f1;
        }
#pragma unroll
    for (int o = 32; o; o >>= 1) {
        s0 += __shfl_xor(s0, o); q0 += __shfl_xor(q0, o);
        s1 += __shfl_xor(s1, o); q1 += __shfl_xor(q1, o);
    }
    const float mu0 = s0 * (1.0f / H_DIM);
    const float rs0 = rsqrtf(q0 * (1.0f / H_DIM) - mu0 * mu0 + 1e-5f);
    const float mu1 = s1 * (1.0f / H_DIM);
    const float rs1 = rsqrtf(q1 * (1.0f / H_DIM) - mu1 * mu1 + 1e-5f);

    float dr0 = 0.f, dd0 = 0.f, dr1 = 0.f, dd1 = 0.f;
#pragma unroll
    for (int j = 0; j < 4; ++j) {
        const int c = j * 512 + lane * 8;
        u16x8 wrv, wdv;
        if (FIN) {
            wrv = *(const u16x8*)&wr[(size_t)e * H_DIM + c];
            wdv = *(const u16x8*)&wd[(size_t)e * H_DIM + c];
        }
        u16x8 ov0, ov1;
#pragma unroll
        for (int k = 0; k < 8; ++k) {
            const float gk = b2f(gv[j][k]), bk = b2f(bv[j][k]);
            const float y0 = (b2f(zv[0][j][k]) - mu0) * rs0 * gk + bk;
            const float y1 = (b2f(zv[1][j][k]) - mu1) * rs1 * gk + bk;
            float g0 = gelu_f(y0), g1 = gelu_f(y1);
            if (RES) { g0 += b2f(hv[0][j][k]); g1 += b2f(hv[1][j][k]); }
            if (FIN) {
                const float wrk = b2f(wrv[k]), wdk = b2f(wdv[k]);
                dr0 += g0 * wrk; dd0 += g0 * wdk;
                dr1 += g1 * wrk; dd1 += g1 * wdk;
            }
            ov0[k] = f2b(g0); ov1[k] = f2b(g1);
        }
        *(u16x8*)&h[base0 + c] = ov0;
        *(u16x8*)&h[base0 + H_DIM + c] = ov1;
    }
    if (FIN) {
#pragma unroll
        for (int o = 32; o; o >>= 1) {
            dr0 += __shfl_xor(dr0, o); dd0 += __shfl_xor(dd0, o);
            dr1 += __shfl_xor(dr1, o); dd1 += __shfl_xor(dd1, o);
        }
        if (lane == 0) {
            atomicAdd(&sum_rew[row0], dr0 + br[e]);
            atomicAdd(&sum_done[row0], 1.0f / (1.0f + __expf(-(dd0 + bd[e]))));
            atomicAdd(&sum_rew[row0 + 1], dr1 + br[e]);
            atomicAdd(&sum_done[row0 + 1], 1.0f / (1.0f + __expf(-(dd1 + bd[e]))));
        }
    }
}

// ---------------- reward/done heads (EB==1 fallback only) --------------------
__global__ __launch_bounds__(256) void k_rewdone(
    const u16* __restrict__ hB, const float* __restrict__ Wr, const float* __restrict__ Wd,
    const float* __restrict__ br, const float* __restrict__ bd,
    float* __restrict__ sum_rew, float* __restrict__ sum_done)
{
    const int e = blockIdx.z;
    const int lane = threadIdx.x & 63;
    const int b = blockIdx.x * 4 + (threadIdx.x >> 6);
    const u16* hrow = hB + ((size_t)e * B_SZ + b) * H_DIM;
    const float* wr_ = Wr + (size_t)e * H_DIM;
    const float* wd_ = Wd + (size_t)e * H_DIM;
    float dr = 0.f, dd = 0.f;
#pragma unroll
    for (int j = 0; j < 4; ++j) {
        const int o = j * 512 + lane * 8;
        u16x8 hv = *(const u16x8*)&hrow[o];
#pragma unroll
        for (int k = 0; k < 8; ++k) {
            const float f = b2f(hv[k]);
            dr += f * wr_[o + k];
            dd += f * wd_[o + k];
        }
    }
#pragma unroll
    for (int o = 32; o; o >>= 1) { dr += __shfl_xor(dr, o); dd += __shfl_xor(dd, o); }
    if (lane == 0) {
        atomicAdd(&sum_rew[b], dr + br[e]);
        atomicAdd(&sum_done[b], 1.0f / (1.0f + expf(-(dd + bd[e]))));
    }
}

// ---------------- finalize: mean/var over E ---------------------------------
template<int FB>
__global__ __launch_bounds__(256) void k_final(
    const float* __restrict__ P, const float* __restrict__ sum_st,
    const float* __restrict__ sq_st, const float* __restrict__ sum_rew,
    const float* __restrict__ sum_done, float* __restrict__ out)
{
    const int b = blockIdx.x, t = threadIdx.x;
    float vs = 0.f;
#pragma unroll
    for (int k = 0; k < 2; ++k) {
        const int s = t + k * 256;
        const size_t i = (size_t)b * S_DIM + s;
        float S1, S2;
        if (FB == 0) {
            S1 = 0.f; S2 = 0.f;
#pragma unroll
            for (int e = 0; e < 8; ++e) {
                const float c = P[(size_t)e * OUT_MS + i];
                S1 += c; S2 += c * c;
            }
        } else { S1 = sum_st[i]; S2 = sq_st[i]; }
        out[i] = S1 * 0.125f;
        vs += (S2 - S1 * S1 * 0.125f) * (1.0f / 7.0f);
    }
#pragma unroll
    for (int o = 32; o; o >>= 1) vs += __shfl_xor(vs, o);
    __shared__ float rv[4];
    if ((t & 63) == 0) rv[t >> 6] = vs;
    __syncthreads();
    if (t == 0) {
        const float tot = rv[0] + rv[1] + rv[2] + rv[3];
        out[OUT_MS + b] = sum_rew[b] * 0.125f;
        out[OUT_MS + B_SZ + b] = sum_done[b] * 0.125f;
        out[OUT_MS + 2 * B_SZ + b] = tot * (1.0f / S_DIM);
    }
}

extern "C" void kernel_launch(void* const* d_in, const int* in_sizes, int n_in,
                              void* d_out, int out_size, void* d_ws, size_t ws_size,
                              hipStream_t stream) {
    (void)in_sizes; (void)n_in; (void)out_size;
    const float* state   = (const float*)d_in[0];
    const float* action  = (const float*)d_in[1];
    const float* W_in    = (const float*)d_in[2];
    const float* b_in    = (const float*)d_in[3];
    const float* g_in    = (const float*)d_in[4];
    const float* be_in   = (const float*)d_in[5];
    const float* W_h     = (const float*)d_in[6];
    const float* b_h     = (const float*)d_in[7];
    const float* g_h     = (const float*)d_in[8];
    const float* be_h    = (const float*)d_in[9];
    const float* W_state = (const float*)d_in[10];
    const float* b_state = (const float*)d_in[11];
    const float* W_rew   = (const float*)d_in[12];
    const float* b_rew   = (const float*)d_in[13];
    const float* W_done  = (const float*)d_in[14];
    const float* b_done  = (const float*)d_in[15];
    float* out = (float*)d_out;

    char* ws = (char*)d_ws;
    size_t off = 0;
    auto alloc = [&](size_t bytes) -> void* {
        void* p = ws + off; off += (bytes + 255) & ~((size_t)255); return p;
    };
    const size_t BH = (size_t)B_SZ * H_DIM;       // 16777216
    u16*   xb      = (u16*)alloc((size_t)B_SZ * KIN * 2);
    u16*   Wf_in   = (u16*)alloc((size_t)8 * H_DIM * KIN * 2);
    u16*   Wf_h    = (u16*)alloc((size_t)24 * H_DIM * H_DIM * 2);
    u16*   Wf_st   = (u16*)alloc((size_t)8 * S_DIM * H_DIM * 2);
    u16*   gb16    = (u16*)alloc((size_t)163840 * 2);
    float* sum_st  = (float*)alloc((size_t)B_SZ * S_DIM * 4);
    float* sq_st   = (float*)alloc((size_t)B_SZ * S_DIM * 4);
    float* sum_rew = (float*)alloc((size_t)B_SZ * 4);
    float* sum_done= (float*)alloc((size_t)B_SZ * 4);
    const size_t fixed = off;
    const int EB = (ws_size >= fixed + 2ULL * 8 * BH * 2) ? 8 : 1;
    u16*   hbuf    = (u16*)alloc((size_t)EB * BH * 2);
    u16*   zbuf    = (u16*)alloc((size_t)EB * BH * 2);
    float* Pbuf    = (float*)zbuf;   // batched: f32 next_states alias (dead zbuf)

    u16* g16_in = gb16;
    u16* be16_in = gb16 + 16384;
    u16* g16_h = gb16 + 32768;
    u16* be16_h = gb16 + 81920;
    u16* wr16 = gb16 + 131072;
    u16* wd16 = gb16 + 147456;

    if (EB == 8) {
        hipMemsetAsync(sum_rew, 0, 2 * (size_t)B_SZ * 4, stream);
    } else {
        hipMemsetAsync(sum_st, 0, (2 * (size_t)B_SZ * S_DIM + 2 * B_SZ) * 4, stream);
    }

    k_concat<<<dim3((B_SZ * KIN) / 256), dim3(256), 0, stream>>>(state, action, xb);
    k_cast<<<dim3(640), dim3(256), 0, stream>>>(g_in, be_in, g_h, be_h, W_rew, W_done, gb16);
    // fragment-major weight prep: lines = (Nd/16)*(Kd/64)*2, blocks = lines/4
    k_wfrag16<<<dim3(576, 1, 8),   dim3(256), 0, stream>>>(W_in, Wf_in, KIN, H_DIM);
    k_wfrag16<<<dim3(2048, 1, 24), dim3(256), 0, stream>>>(W_h, Wf_h, H_DIM, H_DIM);
    k_wfrag16<<<dim3(512, 1, 8),   dim3(256), 0, stream>>>(W_state, Wf_st, H_DIM, S_DIM);

    for (int e0 = 0; e0 < 8; e0 += EB) {
        const dim3 gH(32, 8, EB), gS(32, 2, EB), gL(B_SZ / 8, 1, EB), gF(B_SZ / 4, 1, EB);
        k_gemm256<0><<<gH, 512, 0, stream>>>(
            xb, 0, Wf_in + (size_t)e0 * H_DIM * KIN, (size_t)H_DIM * KIN,
            b_in + (size_t)e0 * H_DIM, H_DIM, zbuf, BH,
            nullptr, nullptr, nullptr, H_DIM, KIN);
        k_ln<0, 0><<<gL, 256, 0, stream>>>(zbuf, hbuf,
            g16_in + (size_t)e0 * H_DIM, be16_in + (size_t)e0 * H_DIM, H_DIM,
            nullptr, nullptr, nullptr, nullptr, nullptr, nullptr);
        for (int l = 0; l < 3; ++l) {
            k_gemm256<0><<<gH, 512, 0, stream>>>(
                hbuf, BH, Wf_h + ((size_t)e0 * 3 + l) * H_DIM * H_DIM, (size_t)3 * H_DIM * H_DIM,
                b_h + (size_t)(e0 * 3 + l) * H_DIM, 3 * H_DIM, zbuf, BH,
                nullptr, nullptr, nullptr, H_DIM, H_DIM);
            if (EB == 8 && l == 2) {
                k_ln<1, 1><<<gL, 256, 0, stream>>>(zbuf, hbuf,
                    g16_h + (size_t)(e0 * 3 + l) * H_DIM, be16_h + (size_t)(e0 * 3 + l) * H_DIM,
                    3 * H_DIM, wr16, wd16, b_rew, b_done, sum_rew, sum_done);
            } else {
                k_ln<1, 0><<<gL, 256, 0, stream>>>(zbuf, hbuf,
                    g16_h + (size_t)(e0 * 3 + l) * H_DIM, be16_h + (size_t)(e0 * 3 + l) * H_DIM,
                    3 * H_DIM, nullptr, nullptr, nullptr, nullptr, nullptr, nullptr);
            }
        }
        if (EB == 8) {
            k_gemm256<1><<<gS, 512, 0, stream>>>(
                hbuf, BH, Wf_st, (size_t)S_DIM * H_DIM,
                b_state, S_DIM, (void*)Pbuf, (size_t)OUT_MS,
                state, nullptr, nullptr, S_DIM, H_DIM);
        } else {
            k_gemm256<2><<<gS, 512, 0, stream>>>(
                hbuf, BH, Wf_st + (size_t)e0 * S_DIM * H_DIM, (size_t)S_DIM * H_DIM,
                b_state + (size_t)e0 * S_DIM, S_DIM, (void*)zbuf, 0,
                state, sum_st, sq_st, S_DIM, H_DIM);
            k_rewdone<<<gF, 256, 0, stream>>>(hbuf,
                W_rew + (size_t)e0 * H_DIM, W_done + (size_t)e0 * H_DIM,
                b_rew + e0, b_done + e0, sum_rew, sum_done);
        }
    }
    if (EB == 8)
        k_final<0><<<dim3(B_SZ), dim3(256), 0, stream>>>(Pbuf, nullptr, nullptr, sum_rew, sum_done, out);
    else
        k_final<1><<<dim3(B_SZ), dim3(256), 0, stream>>>(nullptr, sum_st, sq_st, sum_rew, sum_done, out);
}

// Round 13
// 2546.250 us; speedup vs baseline: 1.1757x; 1.1757x over previous
//
#include <hip/hip_runtime.h>
#include <stdint.h>

#define B_SZ  8192
#define S_DIM 512
#define H_DIM 2048
#define KIN   576
#define OUT_MS 4194304  // B*S

typedef unsigned short u16;
typedef u16   u16x8 __attribute__((ext_vector_type(8)));
typedef u16   u16x4 __attribute__((ext_vector_type(4)));
typedef short s16x8 __attribute__((ext_vector_type(8)));
typedef float f32x4 __attribute__((ext_vector_type(4)));

__device__ __forceinline__ float b2f(u16 u) {
    union { unsigned int i; float f; } v; v.i = ((unsigned int)u) << 16; return v.f;
}
__device__ __forceinline__ u16 f2b(float f) {
    union { float f; unsigned int i; } v; v.f = f;
    unsigned int u = v.i;
    return (u16)((u + 0x7FFFu + ((u >> 16) & 1u)) >> 16);  // RNE
}
// tanh-form GELU via sigmoid: y*sigma(1.59577*y*(1+0.044715*y^2)); |err|<=~1e-3
__device__ __forceinline__ float gelu_f(float y) {
    const float t = __expf(-1.5957691216f * y * (1.0f + 0.044715f * y * y));
    return y / (1.0f + t);
}

__device__ __forceinline__ void gload_lds16(const void* gp, void* lp) {
    __builtin_amdgcn_global_load_lds(
        (const __attribute__((address_space(1))) unsigned int*)gp,
        (__attribute__((address_space(3))) unsigned int*)(unsigned int)(uintptr_t)lp,
        16, 0, 0);
}

#define MFMA __builtin_amdgcn_mfma_f32_16x16x32_bf16

// ---------------- concat + cast to bf16 ------------------------------------
__global__ __launch_bounds__(256) void k_concat(
    const float* __restrict__ state, const float* __restrict__ action,
    u16* __restrict__ xb)
{
    int idx = blockIdx.x * 256 + threadIdx.x;
    int b = idx / KIN, c = idx - b * KIN;
    float v = (c < S_DIM) ? state[(size_t)b * S_DIM + c]
                          : action[(size_t)b * 64 + (c - S_DIM)];
    xb[idx] = f2b(v);
}

// ---------------- f32 -> bf16 cast of 6 param arrays into one ws buffer -----
__global__ __launch_bounds__(256) void k_cast(
    const float* __restrict__ p0, const float* __restrict__ p1,
    const float* __restrict__ p2, const float* __restrict__ p3,
    const float* __restrict__ p4, const float* __restrict__ p5,
    u16* __restrict__ dst)
{
    int i = blockIdx.x * 256 + threadIdx.x;   // grid covers 163840
    float v;
    if      (i < 16384)  v = p0[i];
    else if (i < 32768)  v = p1[i - 16384];
    else if (i < 81920)  v = p2[i - 32768];
    else if (i < 131072) v = p3[i - 81920];
    else if (i < 147456) v = p4[i - 131072];
    else                 v = p5[i - 147456];
    dst[i] = f2b(v);
}

// ---------------- f32 [R][C] -> bf16 [C][R] (per-z matrix) -------------------
__global__ __launch_bounds__(256) void k_transpose(
    const float* __restrict__ src, u16* __restrict__ dst, int R, int C)
{
    __shared__ float tile[32][33];
    const int tx = threadIdx.x, ty = threadIdx.y;
    const int c0 = blockIdx.x * 32, r0 = blockIdx.y * 32;
    const size_t mo = (size_t)blockIdx.z * R * C;
    src += mo; dst += mo;
#pragma unroll
    for (int j = 0; j < 4; ++j)
        tile[ty + j * 8][tx] = src[(size_t)(r0 + ty + j * 8) * C + c0 + tx];
    __syncthreads();
#pragma unroll
    for (int j = 0; j < 4; ++j)
        dst[(size_t)(c0 + ty + j * 8) * R + r0 + tx] = f2b(tile[tx][ty + j * 8]);
}

// ---------------- 256x256 GEMM, m201-style 8-phase/2-K-tile (best-measured) --
// C[M,N] = A[M,K](bf16) * Bt[N,K](bf16)^T ; 512 thr = 8 waves (2M x 4N),
// BK=64, LDS 128KiB (buf d = tile parity), st-swizzle both sides,
// per-iteration (2 K-tiles, 8 phases) staging stagger with counted vmcnt(6).
// MODE 0: Z(u16) = bf16(acc+bias); MODE 1: P(f32) = state+acc+bias;
// MODE 2: c = state+acc+bias; sum_o += c; sq_o += c*c (non-atomic, seq e)
template<int MODE>
__global__ __launch_bounds__(512, 2) void k_gemm256(
    const u16* __restrict__ A, size_t sAe,
    const u16* __restrict__ Bt, size_t sBe,
    const float* __restrict__ bias, int sbE,
    void* __restrict__ Zv, size_t sZe,
    const float* __restrict__ st, float* __restrict__ sum_o, float* __restrict__ sq_o,
    int N, int K)
{
    __shared__ __align__(16) u16 lds[2][32768];   // [tile parity][A 32KB | B 32KB]
    const int t = threadIdx.x;
    const int lane = t & 63;
    const int wid = t >> 6;
    const int wm = wid >> 2, wn = wid & 3;

    // locality swizzle: e-major, per-XCD contiguous bx, by fastest (gx % 8 == 0)
    const int gx = gridDim.x, gy = gridDim.y;
    const int linb = blockIdx.x + gx * (blockIdx.y + gy * blockIdx.z);
    const int x  = linb & 7;
    const int s  = linb >> 3;
    const int m_ = (gx * gy) >> 3;
    const int bz = s / m_;
    const int r_ = s - bz * m_;
    const int p_ = r_ / gy;
    const int by = r_ - p_ * gy;
    const int bx = x * (gx >> 3) + p_;
    const int m0 = bx * 256, n0 = by * 256;

    const u16* Ab = A + (size_t)bz * sAe + (size_t)m0 * K;
    const u16* Bb = Bt + (size_t)bz * sBe + (size_t)n0 * K;

    // staging: one load = 64 rows x 64 cols, thread covers 16B, src pre-swizzled
    const int srow = t >> 3;
    const int scol = (((t & 7) ^ (srow & 7)) * 8);
    const u16* gA = Ab + (size_t)srow * K + scol;
    const u16* gB = Bb + (size_t)srow * K + scol;
    u16* lbase = &lds[0][0];
    const int ldst = srow * 64 + (t & 7) * 8;
    const int NT = K >> 6;
    const int NT2 = NT >> 1;

    auto STAGE = [&](int kt, int mat, int r) {
        const u16* gp = (mat ? gB : gA) + (size_t)(r * 64) * K + kt * 64;
        u16* lp = lbase + (kt & 1) * 32768 + mat * 16384 + r * 4096 + ldst;
        gload_lds16(gp, lp);
    };

    // fragment LDS byte offsets (within matrix slab), swizzled reads
    const int fr = lane & 15, hi = lane >> 4;
    const int cswz = (fr & 7) << 4;
    const int ac0 = (hi * 16) ^ cswz;
    const int ac1 = (64 + hi * 16) ^ cswz;
    const int ar0 = (wm * 128 + fr) * 128;
    const int ar1 = (wm * 128 + 16 + fr) * 128;
    int boff[4][2];
#pragma unroll
    for (int nj = 0; nj < 4; ++nj) {
        const int br_ = (wn * 64 + nj * 16 + fr) * 128;
        boff[nj][0] = br_ + ac0;
        boff[nj][1] = br_ + ac1;
    }

    f32x4 acc[8][4];
#pragma unroll
    for (int i = 0; i < 8; ++i)
#pragma unroll
        for (int j = 0; j < 4; ++j) acc[i][j] = (f32x4){0.f, 0.f, 0.f, 0.f};

    s16x8 bfrag[4][2];
    s16x8 af[4];

    const char* LA0 = (const char*)lbase;
    const char* LB0 = LA0 + 32768;
    const char* LA1 = LA0 + 65536;
    const char* LB1 = LA1 + 32768;

#define LOADB(LBx)                                                        \
    _Pragma("unroll") for (int nj = 0; nj < 4; ++nj) {                    \
        bfrag[nj][0] = *(const s16x8*)((LBx) + boff[nj][0]);              \
        bfrag[nj][1] = *(const s16x8*)((LBx) + boff[nj][1]);              \
    }
#define LOADA(LAx, Q)                                                     \
    af[0] = *(const s16x8*)((LAx) + (Q) * 4096 + ar0 + ac0);              \
    af[1] = *(const s16x8*)((LAx) + (Q) * 4096 + ar0 + ac1);              \
    af[2] = *(const s16x8*)((LAx) + (Q) * 4096 + ar1 + ac0);              \
    af[3] = *(const s16x8*)((LAx) + (Q) * 4096 + ar1 + ac1);
#define DOMFMA(Q)                                                         \
    __builtin_amdgcn_s_barrier();                                         \
    __builtin_amdgcn_s_setprio(1);                                        \
    _Pragma("unroll") for (int nj = 0; nj < 4; ++nj) {                    \
        acc[2*(Q)][nj]   = MFMA(af[0], bfrag[nj][0], acc[2*(Q)][nj], 0, 0, 0);   \
        acc[2*(Q)][nj]   = MFMA(af[1], bfrag[nj][1], acc[2*(Q)][nj], 0, 0, 0);   \
        acc[2*(Q)+1][nj] = MFMA(af[2], bfrag[nj][0], acc[2*(Q)+1][nj], 0, 0, 0); \
        acc[2*(Q)+1][nj] = MFMA(af[3], bfrag[nj][1], acc[2*(Q)+1][nj], 0, 0, 0); \
    }                                                                     \
    __builtin_amdgcn_s_setprio(0);
#define WAITV(COND)                                                       \
    if (COND) { asm volatile("s_waitcnt vmcnt(6)" ::: "memory"); }        \
    else      { asm volatile("s_waitcnt vmcnt(0)" ::: "memory"); }        \
    __builtin_amdgcn_sched_barrier(0);

    // prologue: tile0 complete (8 loads), tile1 partial (B all + A r0,r2)
    STAGE(0, 1, 0); STAGE(0, 1, 1); STAGE(0, 1, 2); STAGE(0, 1, 3);
    STAGE(0, 0, 0); STAGE(0, 0, 2); STAGE(0, 0, 1); STAGE(0, 0, 3);
    STAGE(1, 1, 0); STAGE(1, 1, 1); STAGE(1, 1, 2); STAGE(1, 1, 3);
    STAGE(1, 0, 0); STAGE(1, 0, 2);
    asm volatile("s_waitcnt vmcnt(6)" ::: "memory");
    __builtin_amdgcn_sched_barrier(0);
    __builtin_amdgcn_s_barrier();

    for (int i2 = 0; i2 < NT2; ++i2) {
        const int t1 = 2 * i2 + 1, tn0 = t1 + 1, tn1 = t1 + 2;
        const bool h0 = tn0 < NT, h1 = tn1 < NT;
        LOADB(LB0) LOADA(LA0, 0)
        STAGE(t1, 0, 1); STAGE(t1, 0, 3);
        DOMFMA(0)
        __builtin_amdgcn_s_barrier();
        LOADA(LA0, 1)
        if (h0) { STAGE(tn0, 1, 0); STAGE(tn0, 1, 1); }
        DOMFMA(1)
        __builtin_amdgcn_s_barrier();
        LOADA(LA0, 2)
        if (h0) { STAGE(tn0, 1, 2); STAGE(tn0, 1, 3); }
        DOMFMA(2)
        __builtin_amdgcn_s_barrier();
        LOADA(LA0, 3)
        if (h0) { STAGE(tn0, 0, 0); STAGE(tn0, 0, 2); }
        DOMFMA(3)
        WAITV(h0)
        __builtin_amdgcn_s_barrier();
        LOADB(LB1) LOADA(LA1, 0)
        if (h0) { STAGE(tn0, 0, 1); STAGE(tn0, 0, 3); }
        DOMFMA(0)
        __builtin_amdgcn_s_barrier();
        LOADA(LA1, 1)
        if (h1) { STAGE(tn1, 1, 0); STAGE(tn1, 1, 1); }
        DOMFMA(1)
        __builtin_amdgcn_s_barrier();
        LOADA(LA1, 2)
        if (h1) { STAGE(tn1, 1, 2); STAGE(tn1, 1, 3); }
        DOMFMA(2)
        __builtin_amdgcn_s_barrier();
        LOADA(LA1, 3)
        if (h1) { STAGE(tn1, 0, 0); STAGE(tn1, 0, 2); }
        DOMFMA(3)
        WAITV(h1)
        __builtin_amdgcn_s_barrier();
    }
    if (NT & 1) {   // tail tile NT-1 (even parity -> buf0), staged in main loop
        LOADB(LB0) LOADA(LA0, 0) DOMFMA(0)
        __builtin_amdgcn_s_barrier();
        LOADA(LA0, 1) DOMFMA(1)
        __builtin_amdgcn_s_barrier();
        LOADA(LA0, 2) DOMFMA(2)
        __builtin_amdgcn_s_barrier();
        LOADA(LA0, 3) DOMFMA(3)
    }
#undef LOADB
#undef LOADA
#undef DOMFMA
#undef WAITV

    // epilogue: C/D col = lane&15, row = (lane>>4)*4 + reg
    const float* biasp = bias + (size_t)bz * sbE;
    const int rg = lane >> 4;
#pragma unroll
    for (int mi = 0; mi < 8; ++mi) {
        const int rowb = m0 + wm * 128 + mi * 16 + rg * 4;
#pragma unroll
        for (int nj = 0; nj < 4; ++nj) {
            const int col = n0 + wn * 64 + nj * 16 + fr;
            const float bv = biasp[col];
#pragma unroll
            for (int r = 0; r < 4; ++r) {
                const int row = rowb + r;
                const size_t idx = (size_t)row * N + col;
                if (MODE == 0) {
                    ((u16*)Zv)[(size_t)bz * sZe + idx] = f2b(acc[mi][nj][r] + bv);
                } else if (MODE == 1) {
                    const float c = st[idx] + acc[mi][nj][r] + bv;
                    ((float*)Zv)[(size_t)bz * sZe + idx] = c;
                } else {
                    const float c = st[idx] + acc[mi][nj][r] + bv;
                    sum_o[idx] += c;
                    sq_o[idx] += c * c;
                }
            }
        }
    }
}

// ---------------- LayerNorm + GELU (+residual, +fused heads), 2 rows/wave ----
template<int RES, int FIN>
__global__ __launch_bounds__(256) void k_ln(
    const u16* __restrict__ z, u16* __restrict__ h,
    const u16* __restrict__ g, const u16* __restrict__ be, int egb,
    const u16* __restrict__ wr, const u16* __restrict__ wd,
    const float* __restrict__ br, const float* __restrict__ bd,
    float* __restrict__ sum_rew, float* __restrict__ sum_done)
{
    const int lane = threadIdx.x & 63;
    const int w = threadIdx.x >> 6;
    const int e = blockIdx.z;
    const int row0 = blockIdx.x * 8 + w * 2;
    const size_t base0 = ((size_t)e * B_SZ + row0) * H_DIM;
    const u16* gp = g + (size_t)e * egb;
    const u16* bp = be + (size_t)e * egb;

    u16x8 zv[2][4], gv[4], bv[4], hv[2][4];
#pragma unroll
    for (int j = 0; j < 4; ++j) {
        const int c = j * 512 + lane * 8;
        zv[0][j] = *(const u16x8*)&z[base0 + c];
        zv[1][j] = *(const u16x8*)&z[base0 + H_DIM + c];
        gv[j] = *(const u16x8*)&gp[c];
        bv[j] = *(const u16x8*)&bp[c];
        if (RES) {
            hv[0][j] = *(const u16x8*)&h[base0 + c];
            hv[1][j] = *(const u16x8*)&h[base0 + H_DIM + c];
        }
    }
    float s0 = 0.f, q0 = 0.f, s1 = 0.f, q1 = 0.f;
#pragma unroll
    for (int j = 0; j < 4; ++j)
#pragma unroll
        for (int k = 0; k < 8; ++k) {
            const float f0 = b2f(zv[0][j][k]); s0 += f0; q0 += f0 * f0;
            const float f1 = b2f(zv[1][j][k]); s1 += f1; q1 += f1 * f1;
        }
#pragma unroll
    for (int o = 32; o; o >>= 1) {
        s0 += __shfl_xor(s0, o); q0 += __shfl_xor(q0, o);
        s1 += __shfl_xor(s1, o); q1 += __shfl_xor(q1, o);
    }
    const float mu0 = s0 * (1.0f / H_DIM);
    const float rs0 = rsqrtf(q0 * (1.0f / H_DIM) - mu0 * mu0 + 1e-5f);
    const float mu1 = s1 * (1.0f / H_DIM);
    const float rs1 = rsqrtf(q1 * (1.0f / H_DIM) - mu1 * mu1 + 1e-5f);

    float dr0 = 0.f, dd0 = 0.f, dr1 = 0.f, dd1 = 0.f;
#pragma unroll
    for (int j = 0; j < 4; ++j) {
        const int c = j * 512 + lane * 8;
        u16x8 wrv, wdv;
        if (FIN) {
            wrv = *(const u16x8*)&wr[(size_t)e * H_DIM + c];
            wdv = *(const u16x8*)&wd[(size_t)e * H_DIM + c];
        }
        u16x8 ov0, ov1;
#pragma unroll
        for (int k = 0; k < 8; ++k) {
            const float gk = b2f(gv[j][k]), bk = b2f(bv[j][k]);
            const float y0 = (b2f(zv[0][j][k]) - mu0) * rs0 * gk + bk;
            const float y1 = (b2f(zv[1][j][k]) - mu1) * rs1 * gk + bk;
            float g0 = gelu_f(y0), g1 = gelu_f(y1);
            if (RES) { g0 += b2f(hv[0][j][k]); g1 += b2f(hv[1][j][k]); }
            if (FIN) {
                const float wrk = b2f(wrv[k]), wdk = b2f(wdv[k]);
                dr0 += g0 * wrk; dd0 += g0 * wdk;
                dr1 += g1 * wrk; dd1 += g1 * wdk;
            }
            ov0[k] = f2b(g0); ov1[k] = f2b(g1);
        }
        *(u16x8*)&h[base0 + c] = ov0;
        *(u16x8*)&h[base0 + H_DIM + c] = ov1;
    }
    if (FIN) {
#pragma unroll
        for (int o = 32; o; o >>= 1) {
            dr0 += __shfl_xor(dr0, o); dd0 += __shfl_xor(dd0, o);
            dr1 += __shfl_xor(dr1, o); dd1 += __shfl_xor(dd1, o);
        }
        if (lane == 0) {
            atomicAdd(&sum_rew[row0], dr0 + br[e]);
            atomicAdd(&sum_done[row0], 1.0f / (1.0f + __expf(-(dd0 + bd[e]))));
            atomicAdd(&sum_rew[row0 + 1], dr1 + br[e]);
            atomicAdd(&sum_done[row0 + 1], 1.0f / (1.0f + __expf(-(dd1 + bd[e]))));
        }
    }
}

// ---------------- reward/done heads (EB==1 fallback only) --------------------
__global__ __launch_bounds__(256) void k_rewdone(
    const u16* __restrict__ hB, const float* __restrict__ Wr, const float* __restrict__ Wd,
    const float* __restrict__ br, const float* __restrict__ bd,
    float* __restrict__ sum_rew, float* __restrict__ sum_done)
{
    const int e = blockIdx.z;
    const int lane = threadIdx.x & 63;
    const int b = blockIdx.x * 4 + (threadIdx.x >> 6);
    const u16* hrow = hB + ((size_t)e * B_SZ + b) * H_DIM;
    const float* wr_ = Wr + (size_t)e * H_DIM;
    const float* wd_ = Wd + (size_t)e * H_DIM;
    float dr = 0.f, dd = 0.f;
#pragma unroll
    for (int j = 0; j < 4; ++j) {
        const int o = j * 512 + lane * 8;
        u16x8 hv = *(const u16x8*)&hrow[o];
#pragma unroll
        for (int k = 0; k < 8; ++k) {
            const float f = b2f(hv[k]);
            dr += f * wr_[o + k];
            dd += f * wd_[o + k];
        }
    }
#pragma unroll
    for (int o = 32; o; o >>= 1) { dr += __shfl_xor(dr, o); dd += __shfl_xor(dd, o); }
    if (lane == 0) {
        atomicAdd(&sum_rew[b], dr + br[e]);
        atomicAdd(&sum_done[b], 1.0f / (1.0f + expf(-(dd + bd[e]))));
    }
}

// ---------------- finalize: mean/var over E ---------------------------------
template<int FB>
__global__ __launch_bounds__(256) void k_final(
    const float* __restrict__ P, const float* __restrict__ sum_st,
    const float* __restrict__ sq_st, const float* __restrict__ sum_rew,
    const float* __restrict__ sum_done, float* __restrict__ out)
{
    const int b = blockIdx.x, t = threadIdx.x;
    float vs = 0.f;
#pragma unroll
    for (int k = 0; k < 2; ++k) {
        const int s = t + k * 256;
        const size_t i = (size_t)b * S_DIM + s;
        float S1, S2;
        if (FB == 0) {
            S1 = 0.f; S2 = 0.f;
#pragma unroll
            for (int e = 0; e < 8; ++e) {
                const float c = P[(size_t)e * OUT_MS + i];
                S1 += c; S2 += c * c;
            }
        } else { S1 = sum_st[i]; S2 = sq_st[i]; }
        out[i] = S1 * 0.125f;
        vs += (S2 - S1 * S1 * 0.125f) * (1.0f / 7.0f);
    }
#pragma unroll
    for (int o = 32; o; o >>= 1) vs += __shfl_xor(vs, o);
    __shared__ float rv[4];
    if ((t & 63) == 0) rv[t >> 6] = vs;
    __syncthreads();
    if (t == 0) {
        const float tot = rv[0] + rv[1] + rv[2] + rv[3];
        out[OUT_MS + b] = sum_rew[b] * 0.125f;
        out[OUT_MS + B_SZ + b] = sum_done[b] * 0.125f;
        out[OUT_MS + 2 * B_SZ + b] = tot * (1.0f / S_DIM);
    }
}

extern "C" void kernel_launch(void* const* d_in, const int* in_sizes, int n_in,
                              void* d_out, int out_size, void* d_ws, size_t ws_size,
                              hipStream_t stream) {
    (void)in_sizes; (void)n_in; (void)out_size;
    const float* state   = (const float*)d_in[0];
    const float* action  = (const float*)d_in[1];
    const float* W_in    = (const float*)d_in[2];
    const float* b_in    = (const float*)d_in[3];
    const float* g_in    = (const float*)d_in[4];
    const float* be_in   = (const float*)d_in[5];
    const float* W_h     = (const float*)d_in[6];
    const float* b_h     = (const float*)d_in[7];
    const float* g_h     = (const float*)d_in[8];
    const float* be_h    = (const float*)d_in[9];
    const float* W_state = (const float*)d_in[10];
    const float* b_state = (const float*)d_in[11];
    const float* W_rew   = (const float*)d_in[12];
    const float* b_rew   = (const float*)d_in[13];
    const float* W_done  = (const float*)d_in[14];
    const float* b_done  = (const float*)d_in[15];
    float* out = (float*)d_out;

    char* ws = (char*)d_ws;
    size_t off = 0;
    auto alloc = [&](size_t bytes) -> void* {
        void* p = ws + off; off += (bytes + 255) & ~((size_t)255); return p;
    };
    const size_t BH = (size_t)B_SZ * H_DIM;       // 16777216
    u16*   xb      = (u16*)alloc((size_t)B_SZ * KIN * 2);
    u16*   Wt_in   = (u16*)alloc((size_t)8 * H_DIM * KIN * 2);
    u16*   Wt_h    = (u16*)alloc((size_t)24 * H_DIM * H_DIM * 2);
    u16*   Wt_st   = (u16*)alloc((size_t)8 * S_DIM * H_DIM * 2);
    u16*   gb16    = (u16*)alloc((size_t)163840 * 2);
    float* sum_st  = (float*)alloc((size_t)B_SZ * S_DIM * 4);
    float* sq_st   = (float*)alloc((size_t)B_SZ * S_DIM * 4);
    float* sum_rew = (float*)alloc((size_t)B_SZ * 4);
    float* sum_done= (float*)alloc((size_t)B_SZ * 4);
    const size_t fixed = off;
    const int EB = (ws_size >= fixed + 2ULL * 8 * BH * 2) ? 8 : 1;
    u16*   hbuf    = (u16*)alloc((size_t)EB * BH * 2);
    u16*   zbuf    = (u16*)alloc((size_t)EB * BH * 2);
    float* Pbuf    = (float*)zbuf;   // batched: f32 next_states alias (dead zbuf)

    u16* g16_in = gb16;
    u16* be16_in = gb16 + 16384;
    u16* g16_h = gb16 + 32768;
    u16* be16_h = gb16 + 81920;
    u16* wr16 = gb16 + 131072;
    u16* wd16 = gb16 + 147456;

    if (EB == 8) {
        hipMemsetAsync(sum_rew, 0, 2 * (size_t)B_SZ * 4, stream);
    } else {
        hipMemsetAsync(sum_st, 0, (2 * (size_t)B_SZ * S_DIM + 2 * B_SZ) * 4, stream);
    }

    k_concat<<<dim3((B_SZ * KIN) / 256), dim3(256), 0, stream>>>(state, action, xb);
    k_cast<<<dim3(640), dim3(256), 0, stream>>>(g_in, be_in, g_h, be_h, W_rew, W_done, gb16);
    k_transpose<<<dim3(H_DIM / 32, KIN / 32, 8),    dim3(32, 8), 0, stream>>>(W_in, Wt_in, KIN, H_DIM);
    k_transpose<<<dim3(H_DIM / 32, H_DIM / 32, 24), dim3(32, 8), 0, stream>>>(W_h, Wt_h, H_DIM, H_DIM);
    k_transpose<<<dim3(S_DIM / 32, H_DIM / 32, 8),  dim3(32, 8), 0, stream>>>(W_state, Wt_st, H_DIM, S_DIM);

    for (int e0 = 0; e0 < 8; e0 += EB) {
        const dim3 gH(32, 8, EB), gS(32, 2, EB), gL(B_SZ / 8, 1, EB), gF(B_SZ / 4, 1, EB);
        k_gemm256<0><<<gH, 512, 0, stream>>>(
            xb, 0, Wt_in + (size_t)e0 * H_DIM * KIN, (size_t)H_DIM * KIN,
            b_in + (size_t)e0 * H_DIM, H_DIM, zbuf, BH,
            nullptr, nullptr, nullptr, H_DIM, KIN);
        k_ln<0, 0><<<gL, 256, 0, stream>>>(zbuf, hbuf,
            g16_in + (size_t)e0 * H_DIM, be16_in + (size_t)e0 * H_DIM, H_DIM,
            nullptr, nullptr, nullptr, nullptr, nullptr, nullptr);
        for (int l = 0; l < 3; ++l) {
            k_gemm256<0><<<gH, 512, 0, stream>>>(
                hbuf, BH, Wt_h + ((size_t)e0 * 3 + l) * H_DIM * H_DIM, (size_t)3 * H_DIM * H_DIM,
                b_h + (size_t)(e0 * 3 + l) * H_DIM, 3 * H_DIM, zbuf, BH,
                nullptr, nullptr, nullptr, H_DIM, H_DIM);
            if (EB == 8 && l == 2) {
                k_ln<1, 1><<<gL, 256, 0, stream>>>(zbuf, hbuf,
                    g16_h + (size_t)(e0 * 3 + l) * H_DIM, be16_h + (size_t)(e0 * 3 + l) * H_DIM,
                    3 * H_DIM, wr16, wd16, b_rew, b_done, sum_rew, sum_done);
            } else {
                k_ln<1, 0><<<gL, 256, 0, stream>>>(zbuf, hbuf,
                    g16_h + (size_t)(e0 * 3 + l) * H_DIM, be16_h + (size_t)(e0 * 3 + l) * H_DIM,
                    3 * H_DIM, nullptr, nullptr, nullptr, nullptr, nullptr, nullptr);
            }
        }
        if (EB == 8) {
            k_gemm256<1><<<gS, 512, 0, stream>>>(
                hbuf, BH, Wt_st, (size_t)S_DIM * H_DIM,
                b_state, S_DIM, (void*)Pbuf, (size_t)OUT_MS,
                state, nullptr, nullptr, S_DIM, H_DIM);
        } else {
            k_gemm256<2><<<gS, 512, 0, stream>>>(
                hbuf, BH, Wt_st + (size_t)e0 * S_DIM * H_DIM, (size_t)S_DIM * H_DIM,
                b_state + (size_t)e0 * S_DIM, S_DIM, (void*)zbuf, 0,
                state, sum_st, sq_st, S_DIM, H_DIM);
            k_rewdone<<<gF, 256, 0, stream>>>(hbuf,
                W_rew + (size_t)e0 * H_DIM, W_done + (size_t)e0 * H_DIM,
                b_rew + e0, b_done + e0, sum_rew, sum_done);
        }
    }
    if (EB == 8)
        k_final<0><<<dim3(B_SZ), dim3(256), 0, stream>>>(Pbuf, nullptr, nullptr, sum_rew, sum_done, out);
    else
        k_final<1><<<dim3(B_SZ), dim3(256), 0, stream>>>(nullptr, sum_st, sq_st, sum_rew, sum_done, out);
}